// Round 6
// baseline (158.206 us; speedup 1.0000x reference)
//
#include <hip/hip_runtime.h>
#include <hip/hip_bf16.h>
#include <math.h>

// Problem constants
#define HIDDEN 512
#define NHEADS 16
#define HDIM   32
#define BATCH  2
#define SEQ    1024
#define MROWS  (BATCH * SEQ)   // 2048
#define NBLK   512             // exact capacity: 2 blocks/CU x 256 CUs

constexpr float LOG2_GAMMA = -0.15200309344504997f; // log2(0.9)

typedef __hip_bfloat16 bf16;
typedef __attribute__((ext_vector_type(8))) short short8;
typedef __attribute__((ext_vector_type(4))) float f32x4;

__device__ __forceinline__ void async16(const void* g, void* l) {
    __builtin_amdgcn_global_load_lds(
        (const __attribute__((address_space(1))) void*)g,
        (__attribute__((address_space(3))) void*)l, 16, 0, 0);
}

__device__ __forceinline__ unsigned short f2bf_bits(float f) {
    bf16 b = __float2bfloat16(f);
    return *(unsigned short*)&b;
}

// ---------------------------------------------------------------------------
// System-coherent stores: sc0 sc1 => write-through past the XCD L2 to the
// memory-side Infinity Cache, visible to all XCDs once vmcnt-drained.
// This removes the need for any buffer_wbl2 at the grid barrier.
// (R5 lesson: the leader wbl2 walk was ~15 us per barrier; R4 lesson:
// per-block release/acquire walks were ~35 us per barrier.)
// ---------------------------------------------------------------------------
__device__ __forceinline__ void store_short_sc(void* p, unsigned v) {
    asm volatile("global_store_short %0, %1, off sc0 sc1"
                 :: "v"(p), "v"(v) : "memory");
}
__device__ __forceinline__ void store_b64_sc(void* p, uint2 v) {
    asm volatile("global_store_dwordx2 %0, %1, off sc0 sc1"
                 :: "v"(p), "v"(v) : "memory");
}
__device__ __forceinline__ void store_b128_sc(void* p, short8 v) {
    asm volatile("global_store_dwordx4 %0, %1, off sc0 sc1"
                 :: "v"(p), "v"(v) : "memory");
}

// ---------------------------------------------------------------------------
// Grid barrier v4: pure relaxed counter, ZERO cache ops.
// Correct because (a) all inter-phase data is written with sc0 sc1 stores
// (globally visible after vmcnt(0)), (b) every inter-phase array is
// write-once -> barrier -> read (no consumer ever caches a pre-barrier
// copy), so no invalidate is needed on the read side.
// Per-phase counters live on separate 128B lines.
// ---------------------------------------------------------------------------
__device__ __forceinline__ void gbar(int* ctl, int p, int tid) {
    __syncthreads();
    if (tid == 0) {
        asm volatile("s_waitcnt vmcnt(0)" ::: "memory");   // sc-stores drained
        int* c = &ctl[p * 32];
        __hip_atomic_fetch_add(c, 1, __ATOMIC_RELAXED, __HIP_MEMORY_SCOPE_AGENT);
        while (__hip_atomic_load(c, __ATOMIC_RELAXED, __HIP_MEMORY_SCOPE_AGENT)
               < NBLK)
            __builtin_amdgcn_s_sleep(8);
    }
    __syncthreads();
}

// ---------------------------------------------------------------------------
// Phase 1: blocks 0-255 transpose+cast the 4 weights (fp32 [512 k][512 n]
// -> bf16 [n][512 k]); blocks 256-511 cast x fp32 -> bf16. sc-stores.
// ---------------------------------------------------------------------------
__device__ __forceinline__ void prep_body(
    char* smem, int blk, int tid,
    const float* __restrict__ x,
    const float* __restrict__ qw, const float* __restrict__ kw,
    const float* __restrict__ vw, const float* __restrict__ ow,
    bf16* __restrict__ xb, bf16* __restrict__ wqkvt, bf16* __restrict__ wot)
{
    if (blk < 256) {
        float (*t)[65] = (float(*)[65])smem;   // 64*65*4 = 16640 B
        const int widx = blk >> 6;
        const int tile = blk & 63;
        const int tk = (tile & 7) * 64, tn = (tile >> 3) * 64;
        const float* w = widx == 0 ? qw : widx == 1 ? kw : widx == 2 ? vw : ow;
        #pragma unroll
        for (int u = 0; u < 4; ++u) {
            const int r = u * 16 + (tid >> 4);
            const int c = (tid & 15) * 4;
            float4 v = *(const float4*)&w[(size_t)(tk + r) * 512 + tn + c];
            t[r][c + 0] = v.x; t[r][c + 1] = v.y; t[r][c + 2] = v.z; t[r][c + 3] = v.w;
        }
        __syncthreads();
        #pragma unroll
        for (int u = 0; u < 2; ++u) {
            const int rr = u * 32 + (tid >> 3);
            const int cc = (tid & 7) * 8;
            alignas(16) unsigned short tmp[8];
            #pragma unroll
            for (int i = 0; i < 8; ++i) tmp[i] = f2bf_bits(t[cc + i][rr]);
            bf16* dst = (widx < 3)
                ? &wqkvt[((size_t)widx * 512 + tn + rr) * 512 + tk + cc]
                : &wot[(size_t)(tn + rr) * 512 + tk + cc];
            store_b128_sc(dst, *(short8*)tmp);
        }
    } else {
        #pragma unroll
        for (int u = 0; u < 4; ++u) {
            const int idx = (blk - 256) * 1024 + u * 256 + tid;
            float4 v = ((const float4*)x)[idx];
            unsigned pk0 = (unsigned)f2bf_bits(v.x) | ((unsigned)f2bf_bits(v.y) << 16);
            unsigned pk1 = (unsigned)f2bf_bits(v.z) | ((unsigned)f2bf_bits(v.w) << 16);
            uint2 pk = {pk0, pk1};
            store_b64_sc(&xb[(size_t)idx * 4], pk);
        }
    }
}

// ---------------------------------------------------------------------------
// Persistent-B MFMA GEMM body (verified baseline arithmetic).
// EPI=1 epilogue uses sc-stores (qkvb crosses a barrier); EPI=0 writes the
// final output with plain stores (kernel-end release handles visibility).
// ---------------------------------------------------------------------------
template<int MS, int EPI>
__device__ __forceinline__ void gemm_body(
    short* Bs, int bx, int by, int tid,
    const bf16* __restrict__ A, const bf16* __restrict__ Bt,
    const float* __restrict__ b0, const float* __restrict__ b1,
    const float* __restrict__ b2,
    float* __restrict__ Cf, bf16* __restrict__ Cb, int ldc)
{
    constexpr int K = 512;
    constexpr int LDB = 520;              // +8 shorts pad -> 2-way aliasing only
    constexpr int TM = MS / 64;

    const int wave = tid >> 6, lane = tid & 63;
    const int fr = lane & 15, quad = lane >> 4;
    const int n0 = bx * 64;
    const int m0 = by * MS;

    // ---- stage B once: row = 1 KB contiguous = one async16 wave-instr
    #pragma unroll
    for (int i = 0; i < 16; ++i) {
        const int row = wave * 16 + i;
        async16(&Bt[(size_t)(n0 + row) * K + lane * 8], &Bs[row * LDB]);
    }
    __syncthreads();   // single barrier; vmcnt drain folded in here

    const bf16* pa = &A[(size_t)(m0 + wave * (MS / 4) + fr) * K + quad * 8];

    f32x4 acc[TM][4] = {};
    #pragma unroll
    for (int ks = 0; ks < 16; ++ks) {
        short8 bfrag[4];
        #pragma unroll
        for (int j = 0; j < 4; ++j)
            bfrag[j] = *(const short8*)&Bs[(j * 16 + fr) * LDB + ks * 32 + quad * 8];
        #pragma unroll
        for (int i = 0; i < TM; ++i) {
            short8 af = *(const short8*)(pa + (size_t)i * 16 * K + ks * 32);
            #pragma unroll
            for (int j = 0; j < 4; ++j)
                acc[i][j] = __builtin_amdgcn_mfma_f32_16x16x32_bf16(
                    af, bfrag[j], acc[i][j], 0, 0, 0);
        }
    }

    // Epilogue. C/D layout: col(n)=lane&15, row(m)=quad*4+reg.
    if (EPI == 1) {
        const int seg = n0 >> 9;   // q/k/v segment (block-uniform)
        const float* bp = seg == 0 ? b0 : seg == 1 ? b1 : b2;
        const float sgn = seg == 0 ? 0.5f : seg == 1 ? -0.5f : 0.0f;
        #pragma unroll
        for (int i = 0; i < TM; ++i) {
            const int mrow = m0 + wave * (MS / 4) + i * 16 + quad * 4;
            float sc[4];
            #pragma unroll
            for (int r = 0; r < 4; ++r)
                sc[r] = exp2f((float)((mrow + r) & 63) * (sgn * LOG2_GAMMA));
            #pragma unroll
            for (int j = 0; j < 4; ++j) {
                const int n = n0 + j * 16 + fr;
                const float bv = bp[n & 511];
                #pragma unroll
                for (int r = 0; r < 4; ++r) {
                    unsigned short h = f2bf_bits((acc[i][j][r] + bv) * sc[r]);
                    store_short_sc(&Cb[(size_t)(mrow + r) * ldc + n], (unsigned)h);
                }
            }
        }
    } else {
        #pragma unroll
        for (int i = 0; i < TM; ++i) {
            const int mrow = m0 + wave * (MS / 4) + i * 16 + quad * 4;
            #pragma unroll
            for (int j = 0; j < 4; ++j) {
                const int n = n0 + j * 16 + fr;
                const float bv = b0[n];
                #pragma unroll
                for (int r = 0; r < 4; ++r)
                    Cf[(size_t)(mrow + r) * ldc + n] = acc[i][j][r] + bv;
            }
        }
    }
}

// ---------------------------------------------------------------------------
// Phase 3: MFMA power attention (verified baseline arithmetic). atc crosses
// a barrier -> sc-stores on the output.
// LDS carve: Qs[64*32] Ks[64*32] Vt[32*80] Ps[64*72]  (22528 B total)
// ---------------------------------------------------------------------------
__device__ __forceinline__ void attn_body(
    char* smem, int chunk, int bh, int tid,
    const bf16* __restrict__ qkv, bf16* __restrict__ atc)
{
    short* Qs = (short*)smem;             // 4096 B
    short* Ks = (short*)(smem + 4096);    // 4096 B
    short* Vt = (short*)(smem + 8192);    // 5120 B  [d][s] stride 80
    short* Ps = (short*)(smem + 13312);   // 9216 B  [t][s] stride 72

    const int wave = tid >> 6, lane = tid & 63;
    const int b = bh >> 4, h = bh & 15;
    const int mb = b * SEQ + chunk * 64;
    const int fr = lane & 15, quad = lane >> 4;

    async16(&qkv[(size_t)(mb + wave * 16 + (lane >> 2)) * 1536 + h * 32 + (lane & 3) * 8],
            &Qs[wave * 512]);

    f32x4 o0 = {}, o1 = {};
    const int jstart = chunk >= 2 ? chunk - 2 : 0;   // gamma^129 ~ 1e-6

    for (int j = jstart; j <= chunk; ++j) {
        __syncthreads();
        const int sb = b * SEQ + j * 64;
        async16(&qkv[(size_t)(sb + wave * 16 + (lane >> 2)) * 1536 + 512 + h * 32 + (lane & 3) * 8],
                &Ks[wave * 512]);
        if (tid < 128) {   // transpose-stage V: pairs of s packed as b32 writes
            const int p = tid >> 2, s = p * 2, dbase = (tid & 3) * 8;
            const short* g = (const short*)&qkv[(size_t)(sb + s) * 1536 + 1024 + h * 32 + dbase];
            short8 v0 = *(const short8*)g;
            short8 v1 = *(const short8*)(g + 1536);
            #pragma unroll
            for (int i = 0; i < 8; ++i) {
                unsigned pk = (unsigned)(unsigned short)v0[i]
                            | ((unsigned)(unsigned short)v1[i] << 16);
                *(unsigned*)&Vt[(dbase + i) * 80 + s] = pk;
            }
        }
        __syncthreads();

        short8 aq = *(const short8*)&Qs[(wave * 16 + fr) * 32 + quad * 8];
        f32x4 sAcc[4] = {};
        #pragma unroll
        for (int nt = 0; nt < 4; ++nt) {
            short8 bk = *(const short8*)&Ks[(nt * 16 + fr) * 32 + quad * 8];
            sAcc[nt] = __builtin_amdgcn_mfma_f32_16x16x32_bf16(aq, bk, sAcc[nt], 0, 0, 0);
        }

        const int dj = chunk - j;
        const float sj = exp2f(64.0f * (float)dj * LOG2_GAMMA);
        const int tbase = wave * 16 + quad * 4;
        #pragma unroll
        for (int nt = 0; nt < 4; ++nt) {
            const int s_l = nt * 16 + fr;
            #pragma unroll
            for (int r = 0; r < 4; ++r) {
                const int t_l = tbase + r;
                float pv = sAcc[nt][r];
                pv = pv * pv * sj;
                if (dj == 0 && s_l > t_l) pv = 0.0f;
                Ps[t_l * 72 + s_l] = (short)f2bf_bits(pv);
            }
        }
        short8 a0 = *(const short8*)&Ps[(wave * 16 + fr) * 72 + quad * 8];
        short8 a1 = *(const short8*)&Ps[(wave * 16 + fr) * 72 + 32 + quad * 8];
        short8 b00 = *(const short8*)&Vt[fr * 80 + quad * 8];
        short8 b01 = *(const short8*)&Vt[fr * 80 + 32 + quad * 8];
        short8 b10 = *(const short8*)&Vt[(16 + fr) * 80 + quad * 8];
        short8 b11 = *(const short8*)&Vt[(16 + fr) * 80 + 32 + quad * 8];
        o0 = __builtin_amdgcn_mfma_f32_16x16x32_bf16(a0, b00, o0, 0, 0, 0);
        o0 = __builtin_amdgcn_mfma_f32_16x16x32_bf16(a1, b01, o0, 0, 0, 0);
        o1 = __builtin_amdgcn_mfma_f32_16x16x32_bf16(a0, b10, o1, 0, 0, 0);
        o1 = __builtin_amdgcn_mfma_f32_16x16x32_bf16(a1, b11, o1, 0, 0, 0);
    }

    #pragma unroll
    for (int r = 0; r < 4; ++r) {
        const size_t row = mb + wave * 16 + quad * 4 + r;
        const int col = h * 32 + fr;
        store_short_sc(&atc[row * 512 + col],      (unsigned)f2bf_bits(o0[r]));
        store_short_sc(&atc[row * 512 + col + 16], (unsigned)f2bf_bits(o1[r]));
    }
}

// ---------------------------------------------------------------------------
// Fused pipeline, plain launch: 512 blocks x 256 threads, verified resident
// (R3-R5 passed): LDS 66560x2=133120<=163840, VGPR 88<=128, 8 waves/CU.
// Inter-phase visibility via sc0/sc1 write-through stores; barriers are
// pure relaxed counters (zero cache maintenance).
// ---------------------------------------------------------------------------
__global__ __launch_bounds__(256, 2) void fused_pipeline(
    const float* __restrict__ x,
    const float* __restrict__ qw, const float* __restrict__ kw,
    const float* __restrict__ vw, const float* __restrict__ ow,
    const float* __restrict__ qb, const float* __restrict__ kb,
    const float* __restrict__ vb, const float* __restrict__ ob,
    float* __restrict__ out,
    bf16* __restrict__ xb, bf16* __restrict__ wqkvt, bf16* __restrict__ wot,
    bf16* __restrict__ qkvb, bf16* __restrict__ atc,
    int* __restrict__ ctl)
{
    __shared__ alignas(16) char smem[64 * 520 * 2];   // 66560 B union

    const int bid = blockIdx.x;
    const int tid = threadIdx.x;

    // Phase 1: weight transpose+cast / x cast (512 virtual blocks)
    prep_body(smem, bid, tid, x, qw, kw, vw, ow, xb, wqkvt, wot);

    gbar(ctl, 1, tid);

    // Phase 2: QKV GEMM [2048][512] x [1536][512]^T -> bf16 qkvb (scaled)
    if (bid < 384)
        gemm_body<128, 1>((short*)smem, bid % 24, bid / 24, tid,
                          xb, wqkvt, qb, kb, vb, nullptr, qkvb, 1536);

    gbar(ctl, 2, tid);

    // Phase 3: power attention (512 virtual blocks: 16 chunks x 32 bh)
    attn_body(smem, bid & 15, bid >> 4, tid, qkvb, atc);

    gbar(ctl, 3, tid);

    // Phase 4: output GEMM [2048][512] x [512][512]^T -> fp32 out
    if (bid < 256)
        gemm_body<64, 0>((short*)smem, bid & 7, bid >> 3, tid,
                         atc, wot, ob, nullptr, nullptr, out, nullptr, 512);
}

// ---------------------------------------------------------------------------
extern "C" void kernel_launch(void* const* d_in, const int* in_sizes, int n_in,
                              void* d_out, int out_size, void* d_ws, size_t ws_size,
                              hipStream_t stream)
{
    const float* x  = (const float*)d_in[0];
    const float* qw = (const float*)d_in[1];
    const float* qb = (const float*)d_in[2];
    const float* kw = (const float*)d_in[3];
    const float* kb = (const float*)d_in[4];
    const float* vw = (const float*)d_in[5];
    const float* vb = (const float*)d_in[6];
    const float* ow = (const float*)d_in[7];
    const float* ob = (const float*)d_in[8];
    float* out = (float*)d_out;

    char* w = (char*)d_ws;
    bf16* xb    = (bf16*)(w);                                    // 2 MB   [2048][512]
    bf16* wqkvt = (bf16*)(w + (2ull  << 20));                    // 1.5 MB [1536][512]
    bf16* wot   = (bf16*)(w + (2ull  << 20) + (1536ull << 10));  // 0.5 MB [512][512]
    bf16* qkvb  = (bf16*)(w + (4ull  << 20));                    // 6 MB   [2048][1536]
    bf16* atc   = (bf16*)(w + (10ull << 20));                    // 2 MB   [2048][512]
    int*  ctl   = (int*)(w + (12ull << 20));                     // barrier counters

    // Zero barrier counters every replay (graph node before the kernel).
    hipMemsetAsync(ctl, 0, 512, stream);

    fused_pipeline<<<NBLK, 256, 0, stream>>>(
        x, qw, kw, vw, ow, qb, kb, vb, ob, out,
        xb, wqkvt, wot, qkvb, atc, ctl);
}

// Round 7
// 101.994 us; speedup vs baseline: 1.5511x; 1.5511x over previous
//
#include <hip/hip_runtime.h>
#include <hip/hip_bf16.h>
#include <math.h>

// Problem constants
#define HIDDEN 512
#define NHEADS 16
#define HDIM   32
#define BATCH  2
#define SEQ    1024
#define MROWS  (BATCH * SEQ)   // 2048

constexpr float LOG2_GAMMA = -0.15200309344504997f; // log2(0.9)

typedef __hip_bfloat16 bf16;
typedef __attribute__((ext_vector_type(8))) short short8;
typedef __attribute__((ext_vector_type(4))) float f32x4;

__device__ __forceinline__ void async16(const void* g, void* l) {
    __builtin_amdgcn_global_load_lds(
        (const __attribute__((address_space(1))) void*)g,
        (__attribute__((address_space(3))) void*)l, 16, 0, 0);
}

__device__ __forceinline__ unsigned short f2bf_bits(float f) {
    bf16 b = __float2bfloat16(f);
    return *(unsigned short*)&b;
}

// ---------------------------------------------------------------------------
// Fused prep: blocks 0-255 transpose+cast the 4 weights (fp32 [512 k][512 n]
// -> bf16 [n][512 k]); blocks 256-511 cast x fp32 -> bf16.  (R1-verified.)
// ---------------------------------------------------------------------------
__global__ __launch_bounds__(256) void prep(
    const float* __restrict__ x,
    const float* __restrict__ qw, const float* __restrict__ kw,
    const float* __restrict__ vw, const float* __restrict__ ow,
    bf16* __restrict__ xb, bf16* __restrict__ wqkvt, bf16* __restrict__ wot)
{
    const int blk = blockIdx.x, tid = threadIdx.x;
    if (blk < 256) {
        const int widx = blk >> 6;
        const int tile = blk & 63;
        const int tk = (tile & 7) * 64, tn = (tile >> 3) * 64;
        const float* w = widx == 0 ? qw : widx == 1 ? kw : widx == 2 ? vw : ow;
        __shared__ float t[64][65];
        #pragma unroll
        for (int u = 0; u < 4; ++u) {
            const int r = u * 16 + (tid >> 4);
            const int c = (tid & 15) * 4;
            float4 v = *(const float4*)&w[(size_t)(tk + r) * 512 + tn + c];
            t[r][c + 0] = v.x; t[r][c + 1] = v.y; t[r][c + 2] = v.z; t[r][c + 3] = v.w;
        }
        __syncthreads();
        #pragma unroll
        for (int u = 0; u < 2; ++u) {
            const int rr = u * 32 + (tid >> 3);
            const int cc = (tid & 7) * 8;
            alignas(16) unsigned short tmp[8];
            #pragma unroll
            for (int i = 0; i < 8; ++i) tmp[i] = f2bf_bits(t[cc + i][rr]);
            bf16* dst = (widx < 3)
                ? &wqkvt[((size_t)widx * 512 + tn + rr) * 512 + tk + cc]
                : &wot[(size_t)(tn + rr) * 512 + tk + cc];
            *(short8*)dst = *(short8*)tmp;
        }
    } else {
        #pragma unroll
        for (int u = 0; u < 4; ++u) {
            const int idx = (blk - 256) * 1024 + u * 256 + tid;
            float4 v = ((const float4*)x)[idx];
            unsigned pk0 = (unsigned)f2bf_bits(v.x) | ((unsigned)f2bf_bits(v.y) << 16);
            unsigned pk1 = (unsigned)f2bf_bits(v.z) | ((unsigned)f2bf_bits(v.w) << 16);
            uint2 pk = {pk0, pk1};
            *(uint2*)&xb[(size_t)idx * 4] = pk;
        }
    }
}

// ---------------------------------------------------------------------------
// Persistent-B MFMA GEMM (R1-verified arithmetic, retiled for occupancy).
// NS = B-tile columns. NS=32 -> Bs 33.3 KB -> 4 blocks/CU (vs 2 at NS=64),
// doubling waves/SIMD for latency hiding, and QKV grid becomes 768 blocks
// on 1024 resident slots = single round (the old 384-on-512 had a tail:
// half the CUs ran 2 sequential blocks).
// MS = rows per block (wave w owns rows [w*MS/4, ...)). TM = MS/64.
// EPI=1 (QKV): bf16 out, segmented bias + gamma row-scale. EPI=0: fp32+bias.
// ---------------------------------------------------------------------------
template<int MS, int NS, int EPI>
__global__ __launch_bounds__(256, 4) void gemm_persistB(
    const bf16* __restrict__ A, const bf16* __restrict__ Bt,
    const float* __restrict__ b0, const float* __restrict__ b1,
    const float* __restrict__ b2,
    float* __restrict__ Cf, bf16* __restrict__ Cb, int ldc)
{
    constexpr int K = 512;
    constexpr int LDB = 520;              // +8 shorts pad -> 2-way aliasing only
    constexpr int TM = MS / 64;
    constexpr int TN = NS / 16;
    __shared__ alignas(16) short Bs[NS * LDB];   // NS=32: 33280 B -> 4 blocks/CU

    const int tid = threadIdx.x;
    const int wave = tid >> 6, lane = tid & 63;
    const int fr = lane & 15, quad = lane >> 4;
    const int n0 = blockIdx.x * NS;
    const int m0 = blockIdx.y * MS;

    // ---- stage B once: row = 1 KB contiguous = one async16 wave-instr
    #pragma unroll
    for (int i = 0; i < NS / 4; ++i) {
        const int row = wave * (NS / 4) + i;
        async16(&Bt[(size_t)(n0 + row) * K + lane * 8], &Bs[row * LDB]);
    }
    __syncthreads();   // single barrier; vmcnt drain folded in here

    const bf16* pa = &A[(size_t)(m0 + wave * (MS / 4) + fr) * K + quad * 8];

    f32x4 acc[TM][TN] = {};
    #pragma unroll
    for (int ks = 0; ks < 16; ++ks) {
        short8 bfrag[TN];
        #pragma unroll
        for (int j = 0; j < TN; ++j)
            bfrag[j] = *(const short8*)&Bs[(j * 16 + fr) * LDB + ks * 32 + quad * 8];
        #pragma unroll
        for (int i = 0; i < TM; ++i) {
            short8 af = *(const short8*)(pa + (size_t)i * 16 * K + ks * 32);
            #pragma unroll
            for (int j = 0; j < TN; ++j)
                acc[i][j] = __builtin_amdgcn_mfma_f32_16x16x32_bf16(
                    af, bfrag[j], acc[i][j], 0, 0, 0);
        }
    }

    // Epilogue. C/D layout: col(n)=lane&15, row(m)=quad*4+reg.
    if (EPI == 1) {
        const int seg = n0 >> 9;   // q/k/v segment (block-uniform)
        const float* bp = seg == 0 ? b0 : seg == 1 ? b1 : b2;
        const float sgn = seg == 0 ? 0.5f : seg == 1 ? -0.5f : 0.0f;
        #pragma unroll
        for (int i = 0; i < TM; ++i) {
            const int mrow = m0 + wave * (MS / 4) + i * 16 + quad * 4;
            float sc[4];
            #pragma unroll
            for (int r = 0; r < 4; ++r)
                sc[r] = exp2f((float)((mrow + r) & 63) * (sgn * LOG2_GAMMA));
            #pragma unroll
            for (int j = 0; j < TN; ++j) {
                const int n = n0 + j * 16 + fr;
                const float bv = bp[n & 511];
                #pragma unroll
                for (int r = 0; r < 4; ++r) {
                    unsigned short h = f2bf_bits((acc[i][j][r] + bv) * sc[r]);
                    *(unsigned short*)&Cb[(size_t)(mrow + r) * ldc + n] = h;
                }
            }
        }
    } else {
        #pragma unroll
        for (int i = 0; i < TM; ++i) {
            const int mrow = m0 + wave * (MS / 4) + i * 16 + quad * 4;
            #pragma unroll
            for (int j = 0; j < TN; ++j) {
                const int n = n0 + j * 16 + fr;
                const float bv = b0[n];
                #pragma unroll
                for (int r = 0; r < 4; ++r)
                    Cf[(size_t)(mrow + r) * ldc + n] = acc[i][j][r] + bv;
            }
        }
    }
}

// ---------------------------------------------------------------------------
// MFMA power attention (R1-verified, unchanged). Decay row-scales pre-folded
// into q,k by the QKV GEMM; here S = Q@K^T, P = S^2 * gamma^(64*dj) + causal
// mask, LDS round-trip to A-layout, O += P@V.
// ---------------------------------------------------------------------------
__global__ __launch_bounds__(256) void power_attn_mfma(
    const bf16* __restrict__ qkv, bf16* __restrict__ atc)
{
    __shared__ alignas(16) short Qs[64 * 32];
    __shared__ alignas(16) short Ks[64 * 32];
    __shared__ alignas(16) short Vt[32 * 80];   // V^T [d][s], stride 80
    __shared__ alignas(16) short Ps[64 * 72];   // P [t][s], stride 72

    const int tid = threadIdx.x, wave = tid >> 6, lane = tid & 63;
    const int chunk = blockIdx.x, bh = blockIdx.y;
    const int b = bh >> 4, h = bh & 15;
    const int mb = b * SEQ + chunk * 64;
    const int fr = lane & 15, quad = lane >> 4;

    async16(&qkv[(size_t)(mb + wave * 16 + (lane >> 2)) * 1536 + h * 32 + (lane & 3) * 8],
            &Qs[wave * 512]);

    f32x4 o0 = {}, o1 = {};
    const int jstart = chunk >= 2 ? chunk - 2 : 0;   // gamma^129 ~ 1e-6

    for (int j = jstart; j <= chunk; ++j) {
        __syncthreads();
        const int sb = b * SEQ + j * 64;
        async16(&qkv[(size_t)(sb + wave * 16 + (lane >> 2)) * 1536 + 512 + h * 32 + (lane & 3) * 8],
                &Ks[wave * 512]);
        if (tid < 128) {   // transpose-stage V: pairs of s packed as b32 writes
            const int p = tid >> 2, s = p * 2, dbase = (tid & 3) * 8;
            const short* g = (const short*)&qkv[(size_t)(sb + s) * 1536 + 1024 + h * 32 + dbase];
            short8 v0 = *(const short8*)g;
            short8 v1 = *(const short8*)(g + 1536);
            #pragma unroll
            for (int i = 0; i < 8; ++i) {
                unsigned pk = (unsigned)(unsigned short)v0[i]
                            | ((unsigned)(unsigned short)v1[i] << 16);
                *(unsigned*)&Vt[(dbase + i) * 80 + s] = pk;
            }
        }
        __syncthreads();

        short8 aq = *(const short8*)&Qs[(wave * 16 + fr) * 32 + quad * 8];
        f32x4 sAcc[4] = {};
        #pragma unroll
        for (int nt = 0; nt < 4; ++nt) {
            short8 bk = *(const short8*)&Ks[(nt * 16 + fr) * 32 + quad * 8];
            sAcc[nt] = __builtin_amdgcn_mfma_f32_16x16x32_bf16(aq, bk, sAcc[nt], 0, 0, 0);
        }

        const int dj = chunk - j;
        const float sj = exp2f(64.0f * (float)dj * LOG2_GAMMA);
        const int tbase = wave * 16 + quad * 4;
        #pragma unroll
        for (int nt = 0; nt < 4; ++nt) {
            const int s_l = nt * 16 + fr;
            #pragma unroll
            for (int r = 0; r < 4; ++r) {
                const int t_l = tbase + r;
                float pv = sAcc[nt][r];
                pv = pv * pv * sj;
                if (dj == 0 && s_l > t_l) pv = 0.0f;
                Ps[t_l * 72 + s_l] = (short)f2bf_bits(pv);
            }
        }
        short8 a0 = *(const short8*)&Ps[(wave * 16 + fr) * 72 + quad * 8];
        short8 a1 = *(const short8*)&Ps[(wave * 16 + fr) * 72 + 32 + quad * 8];
        short8 b00 = *(const short8*)&Vt[fr * 80 + quad * 8];
        short8 b01 = *(const short8*)&Vt[fr * 80 + 32 + quad * 8];
        short8 b10 = *(const short8*)&Vt[(16 + fr) * 80 + quad * 8];
        short8 b11 = *(const short8*)&Vt[(16 + fr) * 80 + 32 + quad * 8];
        o0 = __builtin_amdgcn_mfma_f32_16x16x32_bf16(a0, b00, o0, 0, 0, 0);
        o0 = __builtin_amdgcn_mfma_f32_16x16x32_bf16(a1, b01, o0, 0, 0, 0);
        o1 = __builtin_amdgcn_mfma_f32_16x16x32_bf16(a0, b10, o1, 0, 0, 0);
        o1 = __builtin_amdgcn_mfma_f32_16x16x32_bf16(a1, b11, o1, 0, 0, 0);
    }

    #pragma unroll
    for (int r = 0; r < 4; ++r) {
        const size_t row = mb + wave * 16 + quad * 4 + r;
        const int col = h * 32 + fr;
        *(unsigned short*)&atc[row * 512 + col]      = f2bf_bits(o0[r]);
        *(unsigned short*)&atc[row * 512 + col + 16] = f2bf_bits(o1[r]);
    }
}

// ---------------------------------------------------------------------------
extern "C" void kernel_launch(void* const* d_in, const int* in_sizes, int n_in,
                              void* d_out, int out_size, void* d_ws, size_t ws_size,
                              hipStream_t stream)
{
    const float* x  = (const float*)d_in[0];
    const float* qw = (const float*)d_in[1];
    const float* qb = (const float*)d_in[2];
    const float* kw = (const float*)d_in[3];
    const float* kb = (const float*)d_in[4];
    const float* vw = (const float*)d_in[5];
    const float* vb = (const float*)d_in[6];
    const float* ow = (const float*)d_in[7];
    const float* ob = (const float*)d_in[8];
    float* out = (float*)d_out;

    char* w = (char*)d_ws;
    bf16* xb    = (bf16*)(w);                                    // 2 MB   [2048][512]
    bf16* wqkvt = (bf16*)(w + (2ull  << 20));                    // 1.5 MB [1536][512]
    bf16* wot   = (bf16*)(w + (2ull  << 20) + (1536ull << 10));  // 0.5 MB [512][512]
    bf16* qkvb  = (bf16*)(w + (4ull  << 20));                    // 6 MB   [2048][1536]
    bf16* atc   = (bf16*)(w + (10ull << 20));                    // 2 MB   [2048][512]

    prep<<<512, 256, 0, stream>>>(x, qw, kw, vw, ow, xb, wqkvt, wot);

    // QKV GEMM: [2048][512] x [1536][512]^T -> bf16 [2048][1536] (scaled)
    // 48x16 = 768 blocks, 4 blocks/CU -> single residency round.
    gemm_persistB<128, 32, 1><<<dim3(1536 / 32, MROWS / 128), 256, 0, stream>>>(
        xb, wqkvt, qb, kb, vb, nullptr, qkvb, 1536);

    power_attn_mfma<<<dim3(SEQ / 64, BATCH * NHEADS), 256, 0, stream>>>(qkvb, atc);

    // Output GEMM: [2048][512] x [512][512]^T -> fp32 out
    // 16x32 = 512 blocks, 4 blocks/CU.
    gemm_persistB<64, 32, 0><<<dim3(512 / 32, MROWS / 64), 256, 0, stream>>>(
        atc, wot, ob, nullptr, nullptr, out, nullptr, 512);
}

// Round 8
// 99.759 us; speedup vs baseline: 1.5859x; 1.0224x over previous
//
#include <hip/hip_runtime.h>
#include <hip/hip_bf16.h>
#include <math.h>

// Problem constants
#define HIDDEN 512
#define NHEADS 16
#define HDIM   32
#define BATCH  2
#define SEQ    1024
#define MROWS  (BATCH * SEQ)   // 2048

constexpr float LOG2_GAMMA = -0.15200309344504997f; // log2(0.9)

typedef __hip_bfloat16 bf16;
typedef __attribute__((ext_vector_type(8))) short short8;
typedef __attribute__((ext_vector_type(4))) float f32x4;

__device__ __forceinline__ void async16(const void* g, void* l) {
    __builtin_amdgcn_global_load_lds(
        (const __attribute__((address_space(1))) void*)g,
        (__attribute__((address_space(3))) void*)l, 16, 0, 0);
}

__device__ __forceinline__ unsigned short f2bf_bits(float f) {
    bf16 b = __float2bfloat16(f);
    return *(unsigned short*)&b;
}

// ---------------------------------------------------------------------------
// Fused prep: blocks 0-255 transpose+cast the 4 weights (fp32 [512 k][512 n]
// -> bf16 [n][512 k]); blocks 256-511 cast x fp32 -> bf16.  (R1-verified.)
// ---------------------------------------------------------------------------
__global__ __launch_bounds__(256) void prep(
    const float* __restrict__ x,
    const float* __restrict__ qw, const float* __restrict__ kw,
    const float* __restrict__ vw, const float* __restrict__ ow,
    bf16* __restrict__ xb, bf16* __restrict__ wqkvt, bf16* __restrict__ wot)
{
    const int blk = blockIdx.x, tid = threadIdx.x;
    if (blk < 256) {
        const int widx = blk >> 6;
        const int tile = blk & 63;
        const int tk = (tile & 7) * 64, tn = (tile >> 3) * 64;
        const float* w = widx == 0 ? qw : widx == 1 ? kw : widx == 2 ? vw : ow;
        __shared__ float t[64][65];
        #pragma unroll
        for (int u = 0; u < 4; ++u) {
            const int r = u * 16 + (tid >> 4);
            const int c = (tid & 15) * 4;
            float4 v = *(const float4*)&w[(size_t)(tk + r) * 512 + tn + c];
            t[r][c + 0] = v.x; t[r][c + 1] = v.y; t[r][c + 2] = v.z; t[r][c + 3] = v.w;
        }
        __syncthreads();
        #pragma unroll
        for (int u = 0; u < 2; ++u) {
            const int rr = u * 32 + (tid >> 3);
            const int cc = (tid & 7) * 8;
            alignas(16) unsigned short tmp[8];
            #pragma unroll
            for (int i = 0; i < 8; ++i) tmp[i] = f2bf_bits(t[cc + i][rr]);
            bf16* dst = (widx < 3)
                ? &wqkvt[((size_t)widx * 512 + tn + rr) * 512 + tk + cc]
                : &wot[(size_t)(tn + rr) * 512 + tk + cc];
            *(short8*)dst = *(short8*)tmp;
        }
    } else {
        #pragma unroll
        for (int u = 0; u < 4; ++u) {
            const int idx = (blk - 256) * 1024 + u * 256 + tid;
            float4 v = ((const float4*)x)[idx];
            unsigned pk0 = (unsigned)f2bf_bits(v.x) | ((unsigned)f2bf_bits(v.y) << 16);
            unsigned pk1 = (unsigned)f2bf_bits(v.z) | ((unsigned)f2bf_bits(v.w) << 16);
            uint2 pk = {pk0, pk1};
            *(uint2*)&xb[(size_t)idx * 4] = pk;
        }
    }
}

// ---------------------------------------------------------------------------
// Persistent-B MFMA GEMM (R1-verified config restored: NS=64, 2 blocks/CU).
// Block owns a 64-column B-tile for ALL of K=512, staged once into LDS,
// then a fully-unrolled barrier-free K-sweep; A-frags stream from global.
// MS = rows per block. EPI=1 (QKV): bf16 out, segmented bias + gamma
// row-scale. EPI=0: fp32 out + bias.
// ---------------------------------------------------------------------------
template<int MS, int EPI>
__global__ __launch_bounds__(256) void gemm_persistB(
    const bf16* __restrict__ A, const bf16* __restrict__ Bt,
    const float* __restrict__ b0, const float* __restrict__ b1,
    const float* __restrict__ b2,
    float* __restrict__ Cf, bf16* __restrict__ Cb, int ldc)
{
    constexpr int K = 512;
    constexpr int LDB = 520;              // +8 shorts pad -> 2-way aliasing only
    constexpr int TM = MS / 64;
    __shared__ alignas(16) short Bs[64 * LDB];   // 66.5 KB -> 2 blocks/CU

    const int tid = threadIdx.x;
    const int wave = tid >> 6, lane = tid & 63;
    const int fr = lane & 15, quad = lane >> 4;
    const int n0 = blockIdx.x * 64;
    const int m0 = blockIdx.y * MS;

    // ---- stage B once: row = 1 KB contiguous = one async16 wave-instr
    #pragma unroll
    for (int i = 0; i < 16; ++i) {
        const int row = wave * 16 + i;
        async16(&Bt[(size_t)(n0 + row) * K + lane * 8], &Bs[row * LDB]);
    }
    __syncthreads();   // single barrier; vmcnt drain folded in here

    const bf16* pa = &A[(size_t)(m0 + wave * (MS / 4) + fr) * K + quad * 8];

    f32x4 acc[TM][4] = {};
    #pragma unroll
    for (int ks = 0; ks < 16; ++ks) {
        short8 bfrag[4];
        #pragma unroll
        for (int j = 0; j < 4; ++j)
            bfrag[j] = *(const short8*)&Bs[(j * 16 + fr) * LDB + ks * 32 + quad * 8];
        #pragma unroll
        for (int i = 0; i < TM; ++i) {
            short8 af = *(const short8*)(pa + (size_t)i * 16 * K + ks * 32);
            #pragma unroll
            for (int j = 0; j < 4; ++j)
                acc[i][j] = __builtin_amdgcn_mfma_f32_16x16x32_bf16(
                    af, bfrag[j], acc[i][j], 0, 0, 0);
        }
    }

    // Epilogue. C/D layout: col(n)=lane&15, row(m)=quad*4+reg.
    if (EPI == 1) {
        const int seg = n0 >> 9;   // q/k/v segment (block-uniform)
        const float* bp = seg == 0 ? b0 : seg == 1 ? b1 : b2;
        const float sgn = seg == 0 ? 0.5f : seg == 1 ? -0.5f : 0.0f;
        #pragma unroll
        for (int i = 0; i < TM; ++i) {
            const int mrow = m0 + wave * (MS / 4) + i * 16 + quad * 4;
            float sc[4];
            #pragma unroll
            for (int r = 0; r < 4; ++r)
                sc[r] = exp2f((float)((mrow + r) & 63) * (sgn * LOG2_GAMMA));
            #pragma unroll
            for (int j = 0; j < 4; ++j) {
                const int n = n0 + j * 16 + fr;
                const float bv = bp[n & 511];
                #pragma unroll
                for (int r = 0; r < 4; ++r) {
                    unsigned short h = f2bf_bits((acc[i][j][r] + bv) * sc[r]);
                    *(unsigned short*)&Cb[(size_t)(mrow + r) * ldc + n] = h;
                }
            }
        }
    } else {
        #pragma unroll
        for (int i = 0; i < TM; ++i) {
            const int mrow = m0 + wave * (MS / 4) + i * 16 + quad * 4;
            #pragma unroll
            for (int j = 0; j < 4; ++j) {
                const int n = n0 + j * 16 + fr;
                const float bv = b0[n];
                #pragma unroll
                for (int r = 0; r < 4; ++r)
                    Cf[(size_t)(mrow + r) * ldc + n] = acc[i][j][r] + bv;
            }
        }
    }
}

// ---------------------------------------------------------------------------
// MFMA power attention, preload-all-j version.
// R1 structure had 3 serialized {global load -> barrier -> compute} round
// trips per block. Here: ALL K-tiles (async16 -> Ks3[3]) and V-tiles
// (global -> regs) are issued upfront, one barrier drains everything, V is
// staged to LDS, one more barrier, then the compute loop runs with ZERO
// barriers (Ps is wave-local: each wave writes and reads only its own
// 16-row slice, ordered by lgkmcnt within the wave — R1-verified property).
// LDS: Qs 4KB + Ks3 12KB + Vt3 15KB + Ps 9KB = 40KB -> >=4 blocks/CU.
// ---------------------------------------------------------------------------
__global__ __launch_bounds__(256) void power_attn_mfma(
    const bf16* __restrict__ qkv, bf16* __restrict__ atc)
{
    __shared__ alignas(16) short Qs[64 * 32];
    __shared__ alignas(16) short Ks3[3][64 * 32];
    __shared__ alignas(16) short Vt3[3][32 * 80];   // V^T [d][s], stride 80
    __shared__ alignas(16) short Ps[64 * 72];       // P [t][s], stride 72

    const int tid = threadIdx.x, wave = tid >> 6, lane = tid & 63;
    const int chunk = blockIdx.x, bh = blockIdx.y;
    const int b = bh >> 4, h = bh & 15;
    const int mb = b * SEQ + chunk * 64;
    const int fr = lane & 15, quad = lane >> 4;

    const int jstart = chunk >= 2 ? chunk - 2 : 0;   // gamma^129 ~ 1e-6
    const int nj = chunk - jstart + 1;               // 1..3

    // ---- issue ALL global loads upfront ----
    async16(&qkv[(size_t)(mb + wave * 16 + (lane >> 2)) * 1536 + h * 32 + (lane & 3) * 8],
            &Qs[wave * 512]);
    #pragma unroll
    for (int d2 = 0; d2 < 3; ++d2) {
        if (d2 < nj) {
            const int sb = b * SEQ + (jstart + d2) * 64;
            async16(&qkv[(size_t)(sb + wave * 16 + (lane >> 2)) * 1536 + 512 + h * 32 + (lane & 3) * 8],
                    &Ks3[d2][wave * 512]);
        }
    }
    short8 vreg[3][2];
    const int p = tid >> 2, s = p * 2, dbase = (tid & 3) * 8;
    if (tid < 128) {
        #pragma unroll
        for (int d2 = 0; d2 < 3; ++d2) {
            if (d2 < nj) {
                const int sb = b * SEQ + (jstart + d2) * 64;
                const short* g = (const short*)&qkv[(size_t)(sb + s) * 1536 + 1024 + h * 32 + dbase];
                vreg[d2][0] = *(const short8*)g;
                vreg[d2][1] = *(const short8*)(g + 1536);
            }
        }
    }
    __syncthreads();   // drains vmcnt: Qs/Ks3 resident; vreg loads complete

    // ---- stage V^T for all j ----
    if (tid < 128) {
        #pragma unroll
        for (int d2 = 0; d2 < 3; ++d2) {
            if (d2 < nj) {
                #pragma unroll
                for (int i = 0; i < 8; ++i) {
                    unsigned pk = (unsigned)(unsigned short)vreg[d2][0][i]
                                | ((unsigned)(unsigned short)vreg[d2][1][i] << 16);
                    *(unsigned*)&Vt3[d2][(dbase + i) * 80 + s] = pk;
                }
            }
        }
    }
    __syncthreads();

    // ---- barrier-free compute loop ----
    const short8 aq = *(const short8*)&Qs[(wave * 16 + fr) * 32 + quad * 8];
    f32x4 o0 = {}, o1 = {};
    const int tbase = wave * 16 + quad * 4;

    #pragma unroll
    for (int d2 = 0; d2 < 3; ++d2) {
        if (d2 < nj) {
            const int dj = nj - 1 - d2;   // chunk - (jstart+d2)
            f32x4 sAcc[4] = {};
            #pragma unroll
            for (int nt = 0; nt < 4; ++nt) {
                short8 bk = *(const short8*)&Ks3[d2][(nt * 16 + fr) * 32 + quad * 8];
                sAcc[nt] = __builtin_amdgcn_mfma_f32_16x16x32_bf16(aq, bk, sAcc[nt], 0, 0, 0);
            }

            const float sj = exp2f(64.0f * (float)dj * LOG2_GAMMA);
            #pragma unroll
            for (int nt = 0; nt < 4; ++nt) {
                const int s_l = nt * 16 + fr;
                #pragma unroll
                for (int r = 0; r < 4; ++r) {
                    const int t_l = tbase + r;
                    float pv = sAcc[nt][r];
                    pv = pv * pv * sj;
                    if (dj == 0 && s_l > t_l) pv = 0.0f;
                    Ps[t_l * 72 + s_l] = (short)f2bf_bits(pv);
                }
            }
            // Ps wave-local: reads below hit only this wave's rows (lgkmcnt-ordered)
            short8 a0 = *(const short8*)&Ps[(wave * 16 + fr) * 72 + quad * 8];
            short8 a1 = *(const short8*)&Ps[(wave * 16 + fr) * 72 + 32 + quad * 8];
            short8 b00 = *(const short8*)&Vt3[d2][fr * 80 + quad * 8];
            short8 b01 = *(const short8*)&Vt3[d2][fr * 80 + 32 + quad * 8];
            short8 b10 = *(const short8*)&Vt3[d2][(16 + fr) * 80 + quad * 8];
            short8 b11 = *(const short8*)&Vt3[d2][(16 + fr) * 80 + 32 + quad * 8];
            o0 = __builtin_amdgcn_mfma_f32_16x16x32_bf16(a0, b00, o0, 0, 0, 0);
            o0 = __builtin_amdgcn_mfma_f32_16x16x32_bf16(a1, b01, o0, 0, 0, 0);
            o1 = __builtin_amdgcn_mfma_f32_16x16x32_bf16(a0, b10, o1, 0, 0, 0);
            o1 = __builtin_amdgcn_mfma_f32_16x16x32_bf16(a1, b11, o1, 0, 0, 0);
        }
    }

    #pragma unroll
    for (int r = 0; r < 4; ++r) {
        const size_t row = mb + wave * 16 + quad * 4 + r;
        const int col = h * 32 + fr;
        *(unsigned short*)&atc[row * 512 + col]      = f2bf_bits(o0[r]);
        *(unsigned short*)&atc[row * 512 + col + 16] = f2bf_bits(o1[r]);
    }
}

// ---------------------------------------------------------------------------
extern "C" void kernel_launch(void* const* d_in, const int* in_sizes, int n_in,
                              void* d_out, int out_size, void* d_ws, size_t ws_size,
                              hipStream_t stream)
{
    const float* x  = (const float*)d_in[0];
    const float* qw = (const float*)d_in[1];
    const float* qb = (const float*)d_in[2];
    const float* kw = (const float*)d_in[3];
    const float* kb = (const float*)d_in[4];
    const float* vw = (const float*)d_in[5];
    const float* vb = (const float*)d_in[6];
    const float* ow = (const float*)d_in[7];
    const float* ob = (const float*)d_in[8];
    float* out = (float*)d_out;

    char* w = (char*)d_ws;
    bf16* xb    = (bf16*)(w);                                    // 2 MB   [2048][512]
    bf16* wqkvt = (bf16*)(w + (2ull  << 20));                    // 1.5 MB [1536][512]
    bf16* wot   = (bf16*)(w + (2ull  << 20) + (1536ull << 10));  // 0.5 MB [512][512]
    bf16* qkvb  = (bf16*)(w + (4ull  << 20));                    // 6 MB   [2048][1536]
    bf16* atc   = (bf16*)(w + (10ull << 20));                    // 2 MB   [2048][512]

    prep<<<512, 256, 0, stream>>>(x, qw, kw, vw, ow, xb, wqkvt, wot);

    // QKV GEMM: [2048][512] x [1536][512]^T -> bf16 [2048][1536] (scaled)
    gemm_persistB<128, 1><<<dim3(1536 / 64, MROWS / 128), 256, 0, stream>>>(
        xb, wqkvt, qb, kb, vb, nullptr, qkvb, 1536);

    power_attn_mfma<<<dim3(SEQ / 64, BATCH * NHEADS), 256, 0, stream>>>(qkvb, atc);

    // Output GEMM: [2048][512] x [512][512]^T -> fp32 out
    gemm_persistB<64, 0><<<dim3(512 / 64, MROWS / 64), 256, 0, stream>>>(
        atc, wot, ob, nullptr, nullptr, out, nullptr, 512);
}

// Round 9
// 97.906 us; speedup vs baseline: 1.6159x; 1.0189x over previous
//
#include <hip/hip_runtime.h>
#include <hip/hip_bf16.h>
#include <math.h>

// Problem constants
#define HIDDEN 512
#define NHEADS 16
#define HDIM   32
#define BATCH  2
#define SEQ    1024
#define MROWS  (BATCH * SEQ)   // 2048

constexpr float LOG2_GAMMA = -0.15200309344504997f; // log2(0.9)

typedef __hip_bfloat16 bf16;
typedef __attribute__((ext_vector_type(8))) short short8;
typedef __attribute__((ext_vector_type(4))) float f32x4;

__device__ __forceinline__ void async16(const void* g, void* l) {
    __builtin_amdgcn_global_load_lds(
        (const __attribute__((address_space(1))) void*)g,
        (__attribute__((address_space(3))) void*)l, 16, 0, 0);
}

__device__ __forceinline__ unsigned short f2bf_bits(float f) {
    bf16 b = __float2bfloat16(f);
    return *(unsigned short*)&b;
}

// ---------------------------------------------------------------------------
// Fused prep: blocks 0-255 transpose+cast the 4 weights (fp32 [512 k][512 n]
// -> bf16 [n][512 k]); blocks 256-511 cast x fp32 -> bf16.
// ---------------------------------------------------------------------------
__global__ __launch_bounds__(256) void prep(
    const float* __restrict__ x,
    const float* __restrict__ qw, const float* __restrict__ kw,
    const float* __restrict__ vw, const float* __restrict__ ow,
    bf16* __restrict__ xb, bf16* __restrict__ wqkvt, bf16* __restrict__ wot)
{
    const int blk = blockIdx.x, tid = threadIdx.x;
    if (blk < 256) {
        const int widx = blk >> 6;
        const int tile = blk & 63;
        const int tk = (tile & 7) * 64, tn = (tile >> 3) * 64;
        const float* w = widx == 0 ? qw : widx == 1 ? kw : widx == 2 ? vw : ow;
        __shared__ float t[64][65];
        #pragma unroll
        for (int u = 0; u < 4; ++u) {
            const int r = u * 16 + (tid >> 4);
            const int c = (tid & 15) * 4;
            float4 v = *(const float4*)&w[(size_t)(tk + r) * 512 + tn + c];
            t[r][c + 0] = v.x; t[r][c + 1] = v.y; t[r][c + 2] = v.z; t[r][c + 3] = v.w;
        }
        __syncthreads();
        #pragma unroll
        for (int u = 0; u < 2; ++u) {
            const int rr = u * 32 + (tid >> 3);
            const int cc = (tid & 7) * 8;
            alignas(16) unsigned short tmp[8];
            #pragma unroll
            for (int i = 0; i < 8; ++i) tmp[i] = f2bf_bits(t[cc + i][rr]);
            bf16* dst = (widx < 3)
                ? &wqkvt[((size_t)widx * 512 + tn + rr) * 512 + tk + cc]
                : &wot[(size_t)(tn + rr) * 512 + tk + cc];
            *(short8*)dst = *(short8*)tmp;
        }
    } else {
        #pragma unroll
        for (int u = 0; u < 4; ++u) {
            const int idx = (blk - 256) * 1024 + u * 256 + tid;
            float4 v = ((const float4*)x)[idx];
            unsigned pk0 = (unsigned)f2bf_bits(v.x) | ((unsigned)f2bf_bits(v.y) << 16);
            unsigned pk1 = (unsigned)f2bf_bits(v.z) | ((unsigned)f2bf_bits(v.w) << 16);
            uint2 pk = {pk0, pk1};
            *(uint2*)&xb[(size_t)idx * 4] = pk;
        }
    }
}

// ---------------------------------------------------------------------------
// Persistent-B MFMA GEMM: block owns a 64-column B-tile for ALL of K=512,
// staged once into LDS (padded rows, 2-way-max bank aliasing), then a
// fully-unrolled, barrier-free K-sweep: A-frags stream direct from global
// (row-major K-contiguous bf16), B-frags from LDS. No per-K-step barrier.
// MS = rows per block (wave w owns rows [w*MS/4, ...)). TM = MS/64.
// EPI=1 (QKV): bf16 out, segmented bias + gamma row-scale. EPI=0: fp32+bias.
// ---------------------------------------------------------------------------
template<int MS, int EPI>
__global__ __launch_bounds__(256) void gemm_persistB(
    const bf16* __restrict__ A, const bf16* __restrict__ Bt,
    const float* __restrict__ b0, const float* __restrict__ b1,
    const float* __restrict__ b2,
    float* __restrict__ Cf, bf16* __restrict__ Cb, int ldc)
{
    constexpr int K = 512;
    constexpr int LDB = 520;              // +8 shorts pad -> 2-way aliasing only
    constexpr int TM = MS / 64;
    __shared__ alignas(16) short Bs[64 * LDB];   // 66.5 KB -> 2 blocks/CU

    const int tid = threadIdx.x;
    const int wave = tid >> 6, lane = tid & 63;
    const int fr = lane & 15, quad = lane >> 4;
    const int n0 = blockIdx.x * 64;
    const int m0 = blockIdx.y * MS;

    // ---- stage B once: row = 1 KB contiguous = one async16 wave-instr
    #pragma unroll
    for (int i = 0; i < 16; ++i) {
        const int row = wave * 16 + i;
        async16(&Bt[(size_t)(n0 + row) * K + lane * 8], &Bs[row * LDB]);
    }
    __syncthreads();   // single barrier; vmcnt drain folded in here

    const bf16* pa = &A[(size_t)(m0 + wave * (MS / 4) + fr) * K + quad * 8];

    f32x4 acc[TM][4] = {};
    #pragma unroll
    for (int ks = 0; ks < 16; ++ks) {
        short8 bfrag[4];
        #pragma unroll
        for (int j = 0; j < 4; ++j)
            bfrag[j] = *(const short8*)&Bs[(j * 16 + fr) * LDB + ks * 32 + quad * 8];
        #pragma unroll
        for (int i = 0; i < TM; ++i) {
            short8 af = *(const short8*)(pa + (size_t)i * 16 * K + ks * 32);
            #pragma unroll
            for (int j = 0; j < 4; ++j)
                acc[i][j] = __builtin_amdgcn_mfma_f32_16x16x32_bf16(
                    af, bfrag[j], acc[i][j], 0, 0, 0);
        }
    }

    // Epilogue. C/D layout: col(n)=lane&15, row(m)=quad*4+reg.
    if (EPI == 1) {
        const int seg = n0 >> 9;   // q/k/v segment (block-uniform)
        const float* bp = seg == 0 ? b0 : seg == 1 ? b1 : b2;
        const float sgn = seg == 0 ? 0.5f : seg == 1 ? -0.5f : 0.0f;
        #pragma unroll
        for (int i = 0; i < TM; ++i) {
            const int mrow = m0 + wave * (MS / 4) + i * 16 + quad * 4;
            float sc[4];
            #pragma unroll
            for (int r = 0; r < 4; ++r)
                sc[r] = exp2f((float)((mrow + r) & 63) * (sgn * LOG2_GAMMA));
            #pragma unroll
            for (int j = 0; j < 4; ++j) {
                const int n = n0 + j * 16 + fr;
                const float bv = bp[n & 511];
                #pragma unroll
                for (int r = 0; r < 4; ++r) {
                    unsigned short h = f2bf_bits((acc[i][j][r] + bv) * sc[r]);
                    *(unsigned short*)&Cb[(size_t)(mrow + r) * ldc + n] = h;
                }
            }
        }
    } else {
        #pragma unroll
        for (int i = 0; i < TM; ++i) {
            const int mrow = m0 + wave * (MS / 4) + i * 16 + quad * 4;
            #pragma unroll
            for (int j = 0; j < 4; ++j) {
                const int n = n0 + j * 16 + fr;
                const float bv = b0[n];
                #pragma unroll
                for (int r = 0; r < 4; ++r)
                    Cf[(size_t)(mrow + r) * ldc + n] = acc[i][j][r] + bv;
            }
        }
    }
}

// ---------------------------------------------------------------------------
// MFMA power attention (R1-verified version — best measured config).
// Decay row-scales pre-folded into q,k by the QKV GEMM; here S = Q@K^T,
// P = S^2 * gamma^(64*dj) + causal mask, LDS round-trip to A-layout,
// O += P@V.
// ---------------------------------------------------------------------------
__global__ __launch_bounds__(256) void power_attn_mfma(
    const bf16* __restrict__ qkv, bf16* __restrict__ atc)
{
    __shared__ alignas(16) short Qs[64 * 32];
    __shared__ alignas(16) short Ks[64 * 32];
    __shared__ alignas(16) short Vt[32 * 80];   // V^T [d][s], stride 80
    __shared__ alignas(16) short Ps[64 * 72];   // P [t][s], stride 72

    const int tid = threadIdx.x, wave = tid >> 6, lane = tid & 63;
    const int chunk = blockIdx.x, bh = blockIdx.y;
    const int b = bh >> 4, h = bh & 15;
    const int mb = b * SEQ + chunk * 64;
    const int fr = lane & 15, quad = lane >> 4;

    async16(&qkv[(size_t)(mb + wave * 16 + (lane >> 2)) * 1536 + h * 32 + (lane & 3) * 8],
            &Qs[wave * 512]);

    f32x4 o0 = {}, o1 = {};
    const int jstart = chunk >= 2 ? chunk - 2 : 0;   // gamma^129 ~ 1e-6

    for (int j = jstart; j <= chunk; ++j) {
        __syncthreads();
        const int sb = b * SEQ + j * 64;
        async16(&qkv[(size_t)(sb + wave * 16 + (lane >> 2)) * 1536 + 512 + h * 32 + (lane & 3) * 8],
                &Ks[wave * 512]);
        if (tid < 128) {   // transpose-stage V: pairs of s packed as b32 writes
            const int p = tid >> 2, s = p * 2, dbase = (tid & 3) * 8;
            const short* g = (const short*)&qkv[(size_t)(sb + s) * 1536 + 1024 + h * 32 + dbase];
            short8 v0 = *(const short8*)g;
            short8 v1 = *(const short8*)(g + 1536);
            #pragma unroll
            for (int i = 0; i < 8; ++i) {
                unsigned pk = (unsigned)(unsigned short)v0[i]
                            | ((unsigned)(unsigned short)v1[i] << 16);
                *(unsigned*)&Vt[(dbase + i) * 80 + s] = pk;
            }
        }
        __syncthreads();

        short8 aq = *(const short8*)&Qs[(wave * 16 + fr) * 32 + quad * 8];
        f32x4 sAcc[4] = {};
        #pragma unroll
        for (int nt = 0; nt < 4; ++nt) {
            short8 bk = *(const short8*)&Ks[(nt * 16 + fr) * 32 + quad * 8];
            sAcc[nt] = __builtin_amdgcn_mfma_f32_16x16x32_bf16(aq, bk, sAcc[nt], 0, 0, 0);
        }

        const int dj = chunk - j;
        const float sj = exp2f(64.0f * (float)dj * LOG2_GAMMA);
        const int tbase = wave * 16 + quad * 4;
        #pragma unroll
        for (int nt = 0; nt < 4; ++nt) {
            const int s_l = nt * 16 + fr;
            #pragma unroll
            for (int r = 0; r < 4; ++r) {
                const int t_l = tbase + r;
                float pv = sAcc[nt][r];
                pv = pv * pv * sj;
                if (dj == 0 && s_l > t_l) pv = 0.0f;
                Ps[t_l * 72 + s_l] = (short)f2bf_bits(pv);
            }
        }
        short8 a0 = *(const short8*)&Ps[(wave * 16 + fr) * 72 + quad * 8];
        short8 a1 = *(const short8*)&Ps[(wave * 16 + fr) * 72 + 32 + quad * 8];
        short8 b00 = *(const short8*)&Vt[fr * 80 + quad * 8];
        short8 b01 = *(const short8*)&Vt[fr * 80 + 32 + quad * 8];
        short8 b10 = *(const short8*)&Vt[(16 + fr) * 80 + quad * 8];
        short8 b11 = *(const short8*)&Vt[(16 + fr) * 80 + 32 + quad * 8];
        o0 = __builtin_amdgcn_mfma_f32_16x16x32_bf16(a0, b00, o0, 0, 0, 0);
        o0 = __builtin_amdgcn_mfma_f32_16x16x32_bf16(a1, b01, o0, 0, 0, 0);
        o1 = __builtin_amdgcn_mfma_f32_16x16x32_bf16(a0, b10, o1, 0, 0, 0);
        o1 = __builtin_amdgcn_mfma_f32_16x16x32_bf16(a1, b11, o1, 0, 0, 0);
    }

    #pragma unroll
    for (int r = 0; r < 4; ++r) {
        const size_t row = mb + wave * 16 + quad * 4 + r;
        const int col = h * 32 + fr;
        *(unsigned short*)&atc[row * 512 + col]      = f2bf_bits(o0[r]);
        *(unsigned short*)&atc[row * 512 + col + 16] = f2bf_bits(o1[r]);
    }
}

// ---------------------------------------------------------------------------
extern "C" void kernel_launch(void* const* d_in, const int* in_sizes, int n_in,
                              void* d_out, int out_size, void* d_ws, size_t ws_size,
                              hipStream_t stream)
{
    const float* x  = (const float*)d_in[0];
    const float* qw = (const float*)d_in[1];
    const float* qb = (const float*)d_in[2];
    const float* kw = (const float*)d_in[3];
    const float* kb = (const float*)d_in[4];
    const float* vw = (const float*)d_in[5];
    const float* vb = (const float*)d_in[6];
    const float* ow = (const float*)d_in[7];
    const float* ob = (const float*)d_in[8];
    float* out = (float*)d_out;

    char* w = (char*)d_ws;
    bf16* xb    = (bf16*)(w);                                    // 2 MB   [2048][512]
    bf16* wqkvt = (bf16*)(w + (2ull  << 20));                    // 1.5 MB [1536][512]
    bf16* wot   = (bf16*)(w + (2ull  << 20) + (1536ull << 10));  // 0.5 MB [512][512]
    bf16* qkvb  = (bf16*)(w + (4ull  << 20));                    // 6 MB   [2048][1536]
    bf16* atc   = (bf16*)(w + (10ull << 20));                    // 2 MB   [2048][512]

    prep<<<512, 256, 0, stream>>>(x, qw, kw, vw, ow, xb, wqkvt, wot);

    // QKV GEMM: [2048][512] x [1536][512]^T -> bf16 [2048][1536] (scaled)
    gemm_persistB<128, 1><<<dim3(1536 / 64, MROWS / 128), 256, 0, stream>>>(
        xb, wqkvt, qb, kb, vb, nullptr, qkvb, 1536);

    power_attn_mfma<<<dim3(SEQ / 64, BATCH * NHEADS), 256, 0, stream>>>(qkvb, atc);

    // Output GEMM: [2048][512] x [512][512]^T -> fp32 out
    gemm_persistB<64, 0><<<dim3(512 / 64, MROWS / 64), 256, 0, stream>>>(
        atc, wot, ob, nullptr, nullptr, out, nullptr, 512);
}